// Round 1
// baseline (564.221 us; speedup 1.0000x reference)
//
#include <hip/hip_runtime.h>
#include <hip/hip_bf16.h>
#include <cstdint>
#include <cstddef>

// Problem constants (fixed by the reference's setup_inputs)
#define NB     2048      // batch rows
#define DIM    16384     // 32*8*8*8
#define NE     512       // codebook entries
#define NQ     (NB * DIM)       // 33554432 quantized elements
#define NENC   (NB * NE)        // 1048576 encodings elements

typedef float  f32x4  __attribute__((ext_vector_type(4)));
typedef short  short8 __attribute__((ext_vector_type(8)));

// ---------- bf16 split helpers (RNE) ----------
__device__ inline unsigned short f2bf_rne(float f) {
  unsigned u = __float_as_uint(f);
  u += 0x7fffu + ((u >> 16) & 1u);
  return (unsigned short)(u >> 16);
}
__device__ inline float bf2f(unsigned short h) {
  return __uint_as_float(((unsigned)h) << 16);
}

// XOR swizzle inside a [128][32] bf16 LDS array (64 B rows):
// slot bits 4-5 of the k-byte offset are XORed with (row>>1)&3 so that a
// 16-lane column read (rows 0..15, same kByte) hits all 32 banks 2-way max.
__device__ inline int swz(int row, int kByte) {
  return row * 64 + (kByte ^ (((row >> 1) & 3) << 4));
}

// Split a float4 (4 consecutive k) into bf16 hi/lo and store 8B to each array.
__device__ inline void write_split(unsigned short* hiArr, unsigned short* loArr,
                                   int row, int kc, float4 v) {
  float f0 = v.x, f1 = v.y, f2 = v.z, f3 = v.w;
  unsigned short h0 = f2bf_rne(f0), h1 = f2bf_rne(f1), h2 = f2bf_rne(f2), h3 = f2bf_rne(f3);
  unsigned short l0 = f2bf_rne(f0 - bf2f(h0));
  unsigned short l1 = f2bf_rne(f1 - bf2f(h1));
  unsigned short l2 = f2bf_rne(f2 - bf2f(h2));
  unsigned short l3 = f2bf_rne(f3 - bf2f(h3));
  int off = swz(row, kc * 2);  // bytes; kc*2 is 8-aligned, XOR touches bits 4-5 only
  uint2 hv, lv;
  hv.x = (unsigned)h0 | ((unsigned)h1 << 16);
  hv.y = (unsigned)h2 | ((unsigned)h3 << 16);
  lv.x = (unsigned)l0 | ((unsigned)l1 << 16);
  lv.y = (unsigned)l2 | ((unsigned)l3 << 16);
  *(uint2*)((char*)hiArr + off) = hv;
  *(uint2*)((char*)loArr + off) = lv;
}

// Block (256 threads) sum-reduce; result valid on thread 0 only.
__device__ inline float blockReduceSum(float v) {
  #pragma unroll
  for (int o = 32; o > 0; o >>= 1) v += __shfl_down(v, o, 64);
  __shared__ float tmp[4];
  int w = threadIdx.x >> 6, l = threadIdx.x & 63;
  if (l == 0) tmp[w] = v;
  __syncthreads();
  float r = 0.f;
  if (threadIdx.x == 0) r = tmp[0] + tmp[1] + tmp[2] + tmp[3];
  return r;
}

// ---------- K0: codebook norms + zero S / encodings / counts / loss ----------
__global__ void k_init(const float* __restrict__ cb, float* __restrict__ S,
                       float* __restrict__ eN, float* __restrict__ enc,
                       unsigned* __restrict__ counts, double* __restrict__ lossA) {
  int j = blockIdx.x;   // 0..511
  int t = threadIdx.x;  // 256
  const float* row = cb + (size_t)j * DIM;
  float s = 0.f;
  #pragma unroll
  for (int i = 0; i < 16; ++i) {
    float4 v = *(const float4*)(row + i * 1024 + t * 4);
    s += v.x * v.x + v.y * v.y + v.z * v.z + v.w * v.w;
  }
  s = blockReduceSum(s);
  if (t == 0) eN[j] = s;
  float4 z = make_float4(0.f, 0.f, 0.f, 0.f);
  float4* Sp = (float4*)(S + (size_t)j * 2048);
  float4* Ep = (float4*)(enc + (size_t)j * 2048);
  Sp[t] = z; Sp[t + 256] = z;
  Ep[t] = z; Ep[t + 256] = z;
  if (j == 0) {
    counts[t] = 0u; counts[t + 256] = 0u;
    if (t == 0) *lossA = 0.0;
  }
}

// ---------- K1: bf16x3 split-K GEMM, accumulates -2*dot into S ----------
// grid (16 rowblk, 4 colblk, 8 ksplit), 256 threads (4 waves, 2x2 wave grid,
// each wave 64x64 = 4x4 frags of 16x16, BK=32, K-chunk 2048 -> 64 stages).
__global__ __launch_bounds__(256, 2)
void k_gemm(const float* __restrict__ A, const float* __restrict__ Bc,
            float* __restrict__ S) {
  __shared__ unsigned short AsHi[128 * 32], AsLo[128 * 32];
  __shared__ unsigned short BsHi[128 * 32], BsLo[128 * 32];
  int t = threadIdx.x;
  int lane = t & 63, w = t >> 6;
  int rb = blockIdx.x, cblk = blockIdx.y, kz = blockIdx.z;
  int mBase = (w >> 1) * 64, nBase = (w & 1) * 64;
  int l15 = lane & 15, kByte = (lane >> 4) * 16;

  f32x4 acc[4][4] = {};

  int arow = t >> 3;        // 0..31
  int kc = (t & 7) * 4;     // float index within BK=32
  const float* Abase = A + (size_t)(rb * 128) * DIM + kz * 2048 + kc;
  const float* Bbase = Bc + (size_t)(cblk * 128) * DIM + kz * 2048 + kc;

  for (int s = 0; s < 64; ++s) {
    __syncthreads();
    #pragma unroll
    for (int i = 0; i < 4; ++i) {
      int row = arow + i * 32;
      float4 av = *(const float4*)(Abase + (size_t)row * DIM + s * 32);
      write_split(AsHi, AsLo, row, kc, av);
      float4 bv = *(const float4*)(Bbase + (size_t)row * DIM + s * 32);
      write_split(BsHi, BsLo, row, kc, bv);
    }
    __syncthreads();

    short8 ah[4], al[4], bh[4], bl[4];
    #pragma unroll
    for (int m = 0; m < 4; ++m) {
      ah[m] = *(const short8*)((const char*)AsHi + swz(mBase + m * 16 + l15, kByte));
      al[m] = *(const short8*)((const char*)AsLo + swz(mBase + m * 16 + l15, kByte));
      bh[m] = *(const short8*)((const char*)BsHi + swz(nBase + m * 16 + l15, kByte));
      bl[m] = *(const short8*)((const char*)BsLo + swz(nBase + m * 16 + l15, kByte));
    }
    #pragma unroll
    for (int m = 0; m < 4; ++m) {
      #pragma unroll
      for (int n = 0; n < 4; ++n) {
        acc[m][n] = __builtin_amdgcn_mfma_f32_16x16x32_bf16(ah[m], bh[n], acc[m][n], 0, 0, 0);
        acc[m][n] = __builtin_amdgcn_mfma_f32_16x16x32_bf16(ah[m], bl[n], acc[m][n], 0, 0, 0);
        acc[m][n] = __builtin_amdgcn_mfma_f32_16x16x32_bf16(al[m], bh[n], acc[m][n], 0, 0, 0);
      }
    }
  }

  // Epilogue: C/D layout col=lane&15, row=(lane>>4)*4+r (guide §3, m89-verified)
  int r0 = (lane >> 4) * 4;
  #pragma unroll
  for (int m = 0; m < 4; ++m) {
    int gr = rb * 128 + mBase + m * 16 + r0;
    #pragma unroll
    for (int n = 0; n < 4; ++n) {
      int gc = cblk * 128 + nBase + n * 16 + l15;
      #pragma unroll
      for (int r = 0; r < 4; ++r)
        atomicAdd(&S[(size_t)(gr + r) * NE + gc], -2.0f * acc[m][n][r]);
    }
  }
}

// ---------- K2: per-row argmin (dist = ||e||^2 - 2 dot), histogram ----------
__global__ void k_argmin(const float* __restrict__ S, const float* __restrict__ eN,
                         int* __restrict__ idx, unsigned* __restrict__ counts) {
  int w = threadIdx.x >> 6, lane = threadIdx.x & 63;
  int r = blockIdx.x * 4 + w;
  const float* Sr = S + (size_t)r * NE;
  float bd = 3.4e38f; int bj = 0;
  #pragma unroll
  for (int i = 0; i < 8; ++i) {
    int j = i * 64 + lane;
    float d = eN[j] + Sr[j];
    if (d < bd) { bd = d; bj = j; }   // j ascending per-lane -> first-tie kept
  }
  #pragma unroll
  for (int o = 32; o > 0; o >>= 1) {
    float od = __shfl_xor(bd, o, 64);
    int   oj = __shfl_xor(bj, o, 64);
    if (od < bd || (od == bd && oj < bj)) { bd = od; bj = oj; }
  }
  if (lane == 0) { idx[r] = bj; atomicAdd(&counts[bj], 1u); }
}

// ---------- K3: gather quantized + fused loss + one-hot scatter ----------
__global__ void k_gather(const float* __restrict__ x, const float* __restrict__ cbk,
                         const int* __restrict__ idx, float* __restrict__ outq,
                         float* __restrict__ enc, double* __restrict__ lossA) {
  int r = blockIdx.x, t = threadIdx.x;
  int ci = idx[r];
  const float* q  = cbk + (size_t)ci * DIM;
  const float* xr = x + (size_t)r * DIM;
  float* o = outq + (size_t)r * DIM;
  float s = 0.f;
  #pragma unroll
  for (int i = 0; i < 16; ++i) {
    int off = i * 1024 + t * 4;
    float4 qv = *(const float4*)(q + off);
    float4 xv = *(const float4*)(xr + off);
    *(float4*)(o + off) = qv;
    float dx = qv.x - xv.x, dy = qv.y - xv.y;
    float dz = qv.z - xv.z, dw = qv.w - xv.w;
    s += dx * dx + dy * dy + dz * dz + dw * dw;
  }
  s = blockReduceSum(s);
  if (t == 0) {
    atomicAdd(lossA, (double)s);
    enc[(size_t)r * NE + ci] = 1.0f;   // enc pre-zeroed in k_init
  }
}

// ---------- K4: finalize loss + perplexity ----------
__global__ void k_final(const unsigned* __restrict__ counts,
                        const double* __restrict__ lossA,
                        float* __restrict__ outLoss, float* __restrict__ outPerp) {
  int t = threadIdx.x;  // 256
  float h = 0.f;
  #pragma unroll
  for (int i = 0; i < 2; ++i) {
    float p = (float)counts[t + i * 256] * (1.0f / 2048.0f);
    h += p * logf(p + 1e-10f);
  }
  h = blockReduceSum(h);
  if (t == 0) {
    *outLoss = 1.25f * (float)(*lossA * (1.0 / (double)NQ));
    *outPerp = expf(-h);
  }
}

extern "C" void kernel_launch(void* const* d_in, const int* in_sizes, int n_in,
                              void* d_out, int out_size, void* d_ws, size_t ws_size,
                              hipStream_t stream) {
  (void)in_sizes; (void)n_in; (void)out_size; (void)ws_size;
  const float* x  = (const float*)d_in[0];   // inputs  [2048,32,8,8,8]
  const float* cb = (const float*)d_in[1];   // codebook [512,16384]

  float* out     = (float*)d_out;
  float* outLoss = out;                 // [1]
  float* outQ    = out + 1;             // [33554432]
  float* outPerp = out + 1 + NQ;        // [1]
  float* outEnc  = out + 2 + NQ;        // [1048576]

  char* ws = (char*)d_ws;
  float*    S      = (float*)ws;                       // 4 MB: -2*dot accum
  float*    eN     = (float*)(ws + 4194304);           // 2 KB
  int*      idx    = (int*)(ws + 4196352);             // 8 KB
  unsigned* counts = (unsigned*)(ws + 4204544);        // 2 KB
  double*   lossA  = (double*)(ws + 4206592);          // 8 B

  k_init  <<<NE, 256, 0, stream>>>(cb, S, eN, outEnc, counts, lossA);
  k_gemm  <<<dim3(16, 4, 8), 256, 0, stream>>>(x, cb, S);
  k_argmin<<<NB / 4, 256, 0, stream>>>(S, eN, idx, counts);
  k_gather<<<NB, 256, 0, stream>>>(x, cb, idx, outQ, outEnc, lossA);
  k_final <<<1, 256, 0, stream>>>(counts, lossA, outLoss, outPerp);
}

// Round 2
// 455.275 us; speedup vs baseline: 1.2393x; 1.2393x over previous
//
#include <hip/hip_runtime.h>
#include <hip/hip_bf16.h>
#include <cstdint>
#include <cstddef>

// Problem constants (fixed by the reference's setup_inputs)
#define NB     2048      // batch rows
#define DIM    16384     // 32*8*8*8
#define NE     512       // codebook entries
#define NQ     (NB * DIM)       // 33554432 quantized elements
#define NENC   (NB * NE)        // 1048576 encodings elements
#define SPLITS 16               // split-K factor for fast path
#define NKT    (DIM / 32)       // 512 k-chunks of 32

typedef float  f32x4  __attribute__((ext_vector_type(4)));
typedef short  short8 __attribute__((ext_vector_type(8)));

// ---------- bf16 split helpers (RNE) ----------
__device__ inline unsigned short f2bf_rne(float f) {
  unsigned u = __float_as_uint(f);
  u += 0x7fffu + ((u >> 16) & 1u);
  return (unsigned short)(u >> 16);
}
__device__ inline float bf2f(unsigned short h) {
  return __uint_as_float(((unsigned)h) << 16);
}

// XOR swizzle inside a [128][32]-bf16 (64 B/row) tile: byte kByte slot bits
// 4-5 XORed with (row>>1)&3. 16-lane column b128 reads land 2-way (free).
__device__ inline int swz(int row, int kByte) {
  return row * 64 + (kByte ^ (((row >> 1) & 3) << 4));
}

// Split a float4 (4 consecutive k) into bf16 hi/lo, store 8B each (swizzled).
__device__ inline void write_split(unsigned short* hiArr, unsigned short* loArr,
                                   int row, int kc, float4 v) {
  float f0 = v.x, f1 = v.y, f2 = v.z, f3 = v.w;
  unsigned short h0 = f2bf_rne(f0), h1 = f2bf_rne(f1), h2 = f2bf_rne(f2), h3 = f2bf_rne(f3);
  unsigned short l0 = f2bf_rne(f0 - bf2f(h0));
  unsigned short l1 = f2bf_rne(f1 - bf2f(h1));
  unsigned short l2 = f2bf_rne(f2 - bf2f(h2));
  unsigned short l3 = f2bf_rne(f3 - bf2f(h3));
  int off = swz(row, kc * 2);
  uint2 hv, lv;
  hv.x = (unsigned)h0 | ((unsigned)h1 << 16);
  hv.y = (unsigned)h2 | ((unsigned)h3 << 16);
  lv.x = (unsigned)l0 | ((unsigned)l1 << 16);
  lv.y = (unsigned)l2 | ((unsigned)l3 << 16);
  *(uint2*)((char*)hiArr + off) = hv;
  *(uint2*)((char*)loArr + off) = lv;
}

// async global->LDS, 16B per lane. LDS base must be wave-uniform; HW adds lane*16.
__device__ __forceinline__ void gload16(const void* g, void* l) {
  __builtin_amdgcn_global_load_lds(
      (const __attribute__((address_space(1))) unsigned int*)(unsigned long long)(uintptr_t)g,
      (__attribute__((address_space(3))) unsigned int*)(unsigned int)(uintptr_t)l,
      16, 0, 0);
}

// Block (256 threads) sum-reduce; result valid on thread 0 only.
__device__ inline float blockReduceSum(float v) {
  #pragma unroll
  for (int o = 32; o > 0; o >>= 1) v += __shfl_down(v, o, 64);
  __shared__ float tmp[4];
  int w = threadIdx.x >> 6, l = threadIdx.x & 63;
  if (l == 0) tmp[w] = v;
  __syncthreads();
  float r = 0.f;
  if (threadIdx.x == 0) r = tmp[0] + tmp[1] + tmp[2] + tmp[3];
  return r;
}

// =================== FAST PATH ===================

// ---------- P0: fp32 -> pre-swizzled bf16 hi/lo tile panels ----------
// Panel layout: tile (rowPanel, sk) is an 8 KB image of [128 rows][32 k] bf16
// with swz() applied, stored at tileIdx*4096 shorts. Matches the GEMM's
// linear global_load_lds staging + swizzled ds_read_b128 fragment reads.
__global__ void k_prep(const float* __restrict__ x, const float* __restrict__ cb,
                       unsigned short* __restrict__ AhP, unsigned short* __restrict__ AlP,
                       unsigned short* __restrict__ BhP, unsigned short* __restrict__ BlP) {
  int p  = blockIdx.x;   // 0..15: A panels (x), 16..19: B panels (codebook)
  int sk = blockIdx.y;   // 0..511 k-chunk
  int t  = threadIdx.x;
  int q  = t & 7;        // which float4 within the 32-k chunk
  int r0 = t >> 3;       // row 0..31
  const float* src; unsigned short *hiT, *loT;
  if (p < 16) {
    src = x + (size_t)(p * 128) * DIM;
    size_t tb = ((size_t)p * NKT + sk) * 4096;
    hiT = AhP + tb; loT = AlP + tb;
  } else {
    int cblk = p - 16;
    src = cb + (size_t)(cblk * 128) * DIM;
    size_t tb = ((size_t)cblk * NKT + sk) * 4096;
    hiT = BhP + tb; loT = BlP + tb;
  }
  #pragma unroll
  for (int i = 0; i < 4; ++i) {
    int r = r0 + i * 32;
    float4 v = *(const float4*)(src + (size_t)r * DIM + sk * 32 + q * 4);
    write_split(hiT, loT, r, q * 4, v);
  }
}

// ---------- P1: codebook norms + zero enc/counts/loss ----------
__global__ void k_norms(const float* __restrict__ cb, float* __restrict__ eN,
                        float* __restrict__ enc, unsigned* __restrict__ counts,
                        double* __restrict__ lossA) {
  int j = blockIdx.x, t = threadIdx.x;
  const float* row = cb + (size_t)j * DIM;
  float s = 0.f;
  #pragma unroll
  for (int i = 0; i < 16; ++i) {
    float4 v = *(const float4*)(row + i * 1024 + t * 4);
    s += v.x * v.x + v.y * v.y + v.z * v.z + v.w * v.w;
  }
  s = blockReduceSum(s);
  if (t == 0) eN[j] = s;
  float4 z = make_float4(0.f, 0.f, 0.f, 0.f);
  float4* Ep = (float4*)(enc + (size_t)j * 2048);
  Ep[t] = z; Ep[t + 256] = z;
  if (j == 0) {
    counts[t] = 0u; counts[t + 256] = 0u;
    if (t == 0) *lossA = 0.0;
  }
}

// ---------- P2: bf16x3 GEMM, m97-structure (global_load_lds + swizzled LDS) ----------
// grid (16 rowblk, 4 colblk, 16 ksplit) x 256 thr. BK=32, 32 steps per block.
// Per step: 8x global_load_lds_dwordx4 per wave, 16x ds_read_b128, 48 MFMA.
// Plain stores into per-split S slice (no atomics; argmin reduces splits).
__global__ __launch_bounds__(256, 2)
void k_gemm2(const unsigned short* __restrict__ AhP, const unsigned short* __restrict__ AlP,
             const unsigned short* __restrict__ BhP, const unsigned short* __restrict__ BlP,
             float* __restrict__ S) {
  __shared__ unsigned short Ah[4096], Al[4096], Bh[4096], Bl[4096];
  int t = threadIdx.x, lane = t & 63, w = t >> 6;
  int rb = blockIdx.x, cblk = blockIdx.y, kz = blockIdx.z;
  int mBase = (w >> 1) * 64, nBase = (w & 1) * 64;
  int l15 = lane & 15, kByte = (lane >> 4) * 16;
  f32x4 acc[4][4] = {};

  size_t aBase = ((size_t)rb * NKT   + kz * 32) * 8192;  // bytes
  size_t bBase = ((size_t)cblk * NKT + kz * 32) * 8192;
  const char* aH = (const char*)AhP + aBase + t * 16;
  const char* aL = (const char*)AlP + aBase + t * 16;
  const char* bH = (const char*)BhP + bBase + t * 16;
  const char* bL = (const char*)BlP + bBase + t * 16;
  unsigned ldsOff = (unsigned)(w * 1024);  // wave-uniform

  #pragma unroll 1
  for (int s = 0; s < 32; ++s) {
    size_t go = (size_t)s * 8192;
    gload16(aH + go,        (char*)Ah + ldsOff);
    gload16(aH + go + 4096, (char*)Ah + ldsOff + 4096);
    gload16(aL + go,        (char*)Al + ldsOff);
    gload16(aL + go + 4096, (char*)Al + ldsOff + 4096);
    gload16(bH + go,        (char*)Bh + ldsOff);
    gload16(bH + go + 4096, (char*)Bh + ldsOff + 4096);
    gload16(bL + go,        (char*)Bl + ldsOff);
    gload16(bL + go + 4096, (char*)Bl + ldsOff + 4096);
    __syncthreads();   // compiler drains vmcnt before barrier (m97 behavior)

    short8 ahf[4], alf[4], bhf[4], blf[4];
    #pragma unroll
    for (int m = 0; m < 4; ++m) {
      ahf[m] = *(const short8*)((const char*)Ah + swz(mBase + m * 16 + l15, kByte));
      alf[m] = *(const short8*)((const char*)Al + swz(mBase + m * 16 + l15, kByte));
      bhf[m] = *(const short8*)((const char*)Bh + swz(nBase + m * 16 + l15, kByte));
      blf[m] = *(const short8*)((const char*)Bl + swz(nBase + m * 16 + l15, kByte));
    }
    #pragma unroll
    for (int m = 0; m < 4; ++m) {
      #pragma unroll
      for (int n = 0; n < 4; ++n) {
        acc[m][n] = __builtin_amdgcn_mfma_f32_16x16x32_bf16(ahf[m], bhf[n], acc[m][n], 0, 0, 0);
        acc[m][n] = __builtin_amdgcn_mfma_f32_16x16x32_bf16(ahf[m], blf[n], acc[m][n], 0, 0, 0);
        acc[m][n] = __builtin_amdgcn_mfma_f32_16x16x32_bf16(alf[m], bhf[n], acc[m][n], 0, 0, 0);
      }
    }
    __syncthreads();   // protect LDS before restage
  }

  // Epilogue: C/D layout col=lane&15, row=(lane>>4)*4+r (m89-verified)
  int r0v = (lane >> 4) * 4;
  float* Sb = S + (size_t)kz * NB * NE;
  #pragma unroll
  for (int m = 0; m < 4; ++m) {
    int gr = rb * 128 + mBase + m * 16 + r0v;
    #pragma unroll
    for (int n = 0; n < 4; ++n) {
      int gc = cblk * 128 + nBase + n * 16 + l15;
      #pragma unroll
      for (int r = 0; r < 4; ++r)
        Sb[(size_t)(gr + r) * NE + gc] = -2.0f * acc[m][n][r];
    }
  }
}

// ---------- P3: per-row argmin over split-reduced dist, histogram ----------
__global__ void k_argmin_split(const float* __restrict__ S, const float* __restrict__ eN,
                               int* __restrict__ idx, unsigned* __restrict__ counts) {
  int w = threadIdx.x >> 6, lane = threadIdx.x & 63;
  int r = blockIdx.x * 4 + w;
  float bd = 3.4e38f; int bj = 0;
  #pragma unroll
  for (int i = 0; i < 8; ++i) {
    int j = i * 64 + lane;
    float d = eN[j];
    #pragma unroll
    for (int kz = 0; kz < SPLITS; ++kz)
      d += S[((size_t)kz * NB + r) * NE + j];
    if (d < bd) { bd = d; bj = j; }   // ascending j per-lane -> first-tie kept
  }
  #pragma unroll
  for (int o = 32; o > 0; o >>= 1) {
    float od = __shfl_xor(bd, o, 64);
    int   oj = __shfl_xor(bj, o, 64);
    if (od < bd || (od == bd && oj < bj)) { bd = od; bj = oj; }
  }
  if (lane == 0) { idx[r] = bj; atomicAdd(&counts[bj], 1u); }
}

// =================== FALLBACK PATH (round-1, needs only ~4.2 MB ws) ===================

__global__ void k_init(const float* __restrict__ cb, float* __restrict__ S,
                       float* __restrict__ eN, float* __restrict__ enc,
                       unsigned* __restrict__ counts, double* __restrict__ lossA) {
  int j = blockIdx.x, t = threadIdx.x;
  const float* row = cb + (size_t)j * DIM;
  float s = 0.f;
  #pragma unroll
  for (int i = 0; i < 16; ++i) {
    float4 v = *(const float4*)(row + i * 1024 + t * 4);
    s += v.x * v.x + v.y * v.y + v.z * v.z + v.w * v.w;
  }
  s = blockReduceSum(s);
  if (t == 0) eN[j] = s;
  float4 z = make_float4(0.f, 0.f, 0.f, 0.f);
  float4* Sp = (float4*)(S + (size_t)j * 2048);
  float4* Ep = (float4*)(enc + (size_t)j * 2048);
  Sp[t] = z; Sp[t + 256] = z;
  Ep[t] = z; Ep[t + 256] = z;
  if (j == 0) {
    counts[t] = 0u; counts[t + 256] = 0u;
    if (t == 0) *lossA = 0.0;
  }
}

__global__ __launch_bounds__(256, 2)
void k_gemm(const float* __restrict__ A, const float* __restrict__ Bc,
            float* __restrict__ S) {
  __shared__ unsigned short AsHi[128 * 32], AsLo[128 * 32];
  __shared__ unsigned short BsHi[128 * 32], BsLo[128 * 32];
  int t = threadIdx.x;
  int lane = t & 63, w = t >> 6;
  int rb = blockIdx.x, cblk = blockIdx.y, kz = blockIdx.z;
  int mBase = (w >> 1) * 64, nBase = (w & 1) * 64;
  int l15 = lane & 15, kByte = (lane >> 4) * 16;
  f32x4 acc[4][4] = {};
  int arow = t >> 3;
  int kc = (t & 7) * 4;
  const float* Abase = A + (size_t)(rb * 128) * DIM + kz * 2048 + kc;
  const float* Bbase = Bc + (size_t)(cblk * 128) * DIM + kz * 2048 + kc;

  for (int s = 0; s < 64; ++s) {
    __syncthreads();
    #pragma unroll
    for (int i = 0; i < 4; ++i) {
      int row = arow + i * 32;
      float4 av = *(const float4*)(Abase + (size_t)row * DIM + s * 32);
      write_split(AsHi, AsLo, row, kc, av);
      float4 bv = *(const float4*)(Bbase + (size_t)row * DIM + s * 32);
      write_split(BsHi, BsLo, row, kc, bv);
    }
    __syncthreads();
    short8 ah[4], al[4], bh[4], bl[4];
    #pragma unroll
    for (int m = 0; m < 4; ++m) {
      ah[m] = *(const short8*)((const char*)AsHi + swz(mBase + m * 16 + l15, kByte));
      al[m] = *(const short8*)((const char*)AsLo + swz(mBase + m * 16 + l15, kByte));
      bh[m] = *(const short8*)((const char*)BsHi + swz(nBase + m * 16 + l15, kByte));
      bl[m] = *(const short8*)((const char*)BsLo + swz(nBase + m * 16 + l15, kByte));
    }
    #pragma unroll
    for (int m = 0; m < 4; ++m) {
      #pragma unroll
      for (int n = 0; n < 4; ++n) {
        acc[m][n] = __builtin_amdgcn_mfma_f32_16x16x32_bf16(ah[m], bh[n], acc[m][n], 0, 0, 0);
        acc[m][n] = __builtin_amdgcn_mfma_f32_16x16x32_bf16(ah[m], bl[n], acc[m][n], 0, 0, 0);
        acc[m][n] = __builtin_amdgcn_mfma_f32_16x16x32_bf16(al[m], bh[n], acc[m][n], 0, 0, 0);
      }
    }
  }
  int r0 = (lane >> 4) * 4;
  #pragma unroll
  for (int m = 0; m < 4; ++m) {
    int gr = rb * 128 + mBase + m * 16 + r0;
    #pragma unroll
    for (int n = 0; n < 4; ++n) {
      int gc = cblk * 128 + nBase + n * 16 + l15;
      #pragma unroll
      for (int r = 0; r < 4; ++r)
        atomicAdd(&S[(size_t)(gr + r) * NE + gc], -2.0f * acc[m][n][r]);
    }
  }
}

__global__ void k_argmin_flat(const float* __restrict__ S, const float* __restrict__ eN,
                              int* __restrict__ idx, unsigned* __restrict__ counts) {
  int w = threadIdx.x >> 6, lane = threadIdx.x & 63;
  int r = blockIdx.x * 4 + w;
  const float* Sr = S + (size_t)r * NE;
  float bd = 3.4e38f; int bj = 0;
  #pragma unroll
  for (int i = 0; i < 8; ++i) {
    int j = i * 64 + lane;
    float d = eN[j] + Sr[j];
    if (d < bd) { bd = d; bj = j; }
  }
  #pragma unroll
  for (int o = 32; o > 0; o >>= 1) {
    float od = __shfl_xor(bd, o, 64);
    int   oj = __shfl_xor(bj, o, 64);
    if (od < bd || (od == bd && oj < bj)) { bd = od; bj = oj; }
  }
  if (lane == 0) { idx[r] = bj; atomicAdd(&counts[bj], 1u); }
}

// =================== SHARED TAIL ===================

__global__ void k_gather(const float* __restrict__ x, const float* __restrict__ cbk,
                         const int* __restrict__ idx, float* __restrict__ outq,
                         float* __restrict__ enc, double* __restrict__ lossA) {
  int r = blockIdx.x, t = threadIdx.x;
  int ci = idx[r];
  const float* q  = cbk + (size_t)ci * DIM;
  const float* xr = x + (size_t)r * DIM;
  float* o = outq + (size_t)r * DIM;
  float s = 0.f;
  #pragma unroll
  for (int i = 0; i < 16; ++i) {
    int off = i * 1024 + t * 4;
    float4 qv = *(const float4*)(q + off);
    float4 xv = *(const float4*)(xr + off);
    *(float4*)(o + off) = qv;
    float dx = qv.x - xv.x, dy = qv.y - xv.y;
    float dz = qv.z - xv.z, dw = qv.w - xv.w;
    s += dx * dx + dy * dy + dz * dz + dw * dw;
  }
  s = blockReduceSum(s);
  if (t == 0) {
    atomicAdd(lossA, (double)s);
    enc[(size_t)r * NE + ci] = 1.0f;
  }
}

__global__ void k_final(const unsigned* __restrict__ counts,
                        const double* __restrict__ lossA,
                        float* __restrict__ outLoss, float* __restrict__ outPerp) {
  int t = threadIdx.x;
  float h = 0.f;
  #pragma unroll
  for (int i = 0; i < 2; ++i) {
    float p = (float)counts[t + i * 256] * (1.0f / 2048.0f);
    h += p * logf(p + 1e-10f);
  }
  h = blockReduceSum(h);
  if (t == 0) {
    *outLoss = 1.25f * (float)(*lossA * (1.0 / (double)NQ));
    *outPerp = expf(-h);
  }
}

extern "C" void kernel_launch(void* const* d_in, const int* in_sizes, int n_in,
                              void* d_out, int out_size, void* d_ws, size_t ws_size,
                              hipStream_t stream) {
  (void)in_sizes; (void)n_in; (void)out_size;
  const float* x  = (const float*)d_in[0];   // inputs  [2048,32,8,8,8]
  const float* cb = (const float*)d_in[1];   // codebook [512,16384]

  float* out     = (float*)d_out;
  float* outLoss = out;                 // [1]
  float* outQ    = out + 1;             // [33554432]
  float* outPerp = out + 1 + NQ;        // [1]
  float* outEnc  = out + 2 + NQ;        // [1048576]

  char* ws = (char*)d_ws;

  // fast-path ws layout
  const size_t oAh = 0;
  const size_t oAl = 67108864;            // 64 MB
  const size_t oBh = 134217728;           // 128 MB
  const size_t oBl = 150994944;           // 144 MB
  const size_t oS  = 167772160;           // 160 MB (16 x 4 MB)
  const size_t oEN = 234881024;           // 224 MB
  const size_t oIDX = oEN + 2048;
  const size_t oCNT = oIDX + 8192;
  const size_t oLOSS = oCNT + 2048;
  const size_t NEED = oLOSS + 8;

  if (ws_size >= NEED) {
    unsigned short* AhP = (unsigned short*)(ws + oAh);
    unsigned short* AlP = (unsigned short*)(ws + oAl);
    unsigned short* BhP = (unsigned short*)(ws + oBh);
    unsigned short* BlP = (unsigned short*)(ws + oBl);
    float*    S      = (float*)(ws + oS);
    float*    eN     = (float*)(ws + oEN);
    int*      idx    = (int*)(ws + oIDX);
    unsigned* counts = (unsigned*)(ws + oCNT);
    double*   lossA  = (double*)(ws + oLOSS);

    k_prep <<<dim3(20, NKT), 256, 0, stream>>>(x, cb, AhP, AlP, BhP, BlP);
    k_norms<<<NE, 256, 0, stream>>>(cb, eN, outEnc, counts, lossA);
    k_gemm2<<<dim3(16, 4, SPLITS), 256, 0, stream>>>(AhP, AlP, BhP, BlP, S);
    k_argmin_split<<<NB / 4, 256, 0, stream>>>(S, eN, idx, counts);
    k_gather<<<NB, 256, 0, stream>>>(x, cb, idx, outQ, outEnc, lossA);
    k_final<<<1, 256, 0, stream>>>(counts, lossA, outLoss, outPerp);
  } else {
    // round-1 fallback (~4.2 MB scratch)
    float*    S      = (float*)ws;
    float*    eN     = (float*)(ws + 4194304);
    int*      idx    = (int*)(ws + 4196352);
    unsigned* counts = (unsigned*)(ws + 4204544);
    double*   lossA  = (double*)(ws + 4206592);

    k_init  <<<NE, 256, 0, stream>>>(cb, S, eN, outEnc, counts, lossA);
    k_gemm  <<<dim3(16, 4, 8), 256, 0, stream>>>(x, cb, S);
    k_argmin_flat<<<NB / 4, 256, 0, stream>>>(S, eN, idx, counts);
    k_gather<<<NB, 256, 0, stream>>>(x, cb, idx, outQ, outEnc, lossA);
    k_final <<<1, 256, 0, stream>>>(counts, lossA, outLoss, outPerp);
  }
}